// Round 10
// baseline (1019.651 us; speedup 1.0000x reference)
//
#include <hip/hip_runtime.h>
#include <hip/hip_bf16.h>

#define NUM_C  16
#define NUM_D  8
#define RECEPT 512
#define LROW   32768
#define EPS_V  1e-4f

// per-block x slice: 64 windows * 256 stride + 256 overlap = 16640 bf16
// = 33280 B; +headroom for xsw (sets bits 4-6) -> 33536
#define XBYTES 33536

#define P1_REPS 24
#define P2_REPS 20

typedef __attribute__((ext_vector_type(8))) short short8;
typedef __attribute__((ext_vector_type(4))) float f32x4;

__device__ __forceinline__ unsigned short f2bf(float f) {
    unsigned int u = __builtin_bit_cast(unsigned int, f);
    u += 0x7fffu + ((u >> 16) & 1u);   // round-to-nearest-even
    return (unsigned short)(u >> 16);
}

// XOR swizzle on byte address in the bf16 x LDS slice (involution; applied on
// both staging writes and A-fragment reads; breaks the 512B window stride).
__device__ __forceinline__ int xsw(int a) { return a ^ (((a >> 9) & 7) << 4); }

__device__ __forceinline__ ushort4 cvt4(float4 v) {
    ushort4 h;
    h.x = f2bf(v.x); h.y = f2bf(v.y); h.z = f2bf(v.z); h.w = f2bf(v.w);
    return h;
}

// ---------------------------------------------------------------------------
// Prep (16 blocks x 256 thr): per c: G = W W^T + eps I ; chol; Wt = L^{-1} W ;
// store Wt bf16 in MFMA B-fragment order:
//   wfrag[ntile(8)][kk(16)][lane(64)][j(8)]
//   value = Wt[cd = ntile*16 + (lane&15)][r = kk*32 + (lane>>4)*8 + j]
// Also zeroes d_out.
// ---------------------------------------------------------------------------
__global__ void prep_kernel(const float* __restrict__ weight,
                            unsigned short* __restrict__ wfrag,
                            float* __restrict__ out) {
    __shared__ float Wc[NUM_D * RECEPT];
    __shared__ float G[NUM_D][NUM_D];
    __shared__ float Lm[NUM_D][NUM_D];
    const int c = blockIdx.x;
    const int t = threadIdx.x;  // 256 threads

    out[c * 256 + t] = 0.f;
    out[c * 256 + t + 4096] = 0.f;

    const float4* wsrc4 = reinterpret_cast<const float4*>(
        weight + (size_t)c * NUM_D * RECEPT);
    float4* Wc4 = reinterpret_cast<float4*>(Wc);
    #pragma unroll
    for (int i = 0; i < 4; ++i) Wc4[t + i * 256] = wsrc4[t + i * 256];
    __syncthreads();

    if (t < 64) {
        int d = t >> 3, e = t & 7;
        const float4* wd4 = reinterpret_cast<const float4*>(&Wc[d * RECEPT]);
        const float4* we4 = reinterpret_cast<const float4*>(&Wc[e * RECEPT]);
        float s = 0.f;
        #pragma unroll 4
        for (int r4 = 0; r4 < RECEPT / 4; ++r4) {
            float4 a = wd4[r4], bb = we4[r4];
            s += a.x * bb.x + a.y * bb.y + a.z * bb.z + a.w * bb.w;
        }
        if (d == e) s += EPS_V;
        G[d][e] = s;
    }
    __syncthreads();
    if (t == 0) {
        for (int i = 0; i < NUM_D; ++i) {
            float diag = G[i][i];
            for (int k = 0; k < i; ++k) diag -= Lm[i][k] * Lm[i][k];
            float di = sqrtf(diag);
            Lm[i][i] = di;
            float inv = 1.f / di;
            for (int jj = i + 1; jj < NUM_D; ++jj) {
                float s = G[jj][i];
                for (int k = 0; k < i; ++k) s -= Lm[jj][k] * Lm[i][k];
                Lm[jj][i] = s * inv;
            }
        }
    }
    __syncthreads();
    for (int r = t; r < RECEPT; r += 256) {
        float y[NUM_D];
        for (int d = 0; d < NUM_D; ++d) {
            float s = Wc[d * RECEPT + r];
            for (int k = 0; k < d; ++k) s -= Lm[d][k] * y[k];
            y[d] = s / Lm[d][d];
        }
        const int kk = r >> 5;          // 0..15
        const int g  = (r >> 3) & 3;    // k-group within 32
        const int j  = r & 7;
        for (int d = 0; d < NUM_D; ++d) {
            int cd = c * NUM_D + d;
            int ntile = cd >> 4;
            int nl = cd & 15;
            int lane = g * 16 + nl;
            int idx = (((ntile * 16 + kk) * 64) + lane) * 8 + j;
            wfrag[idx] = f2bf(y[d]);
        }
    }
}

// ---------------------------------------------------------------------------
// PROBE 1: staging-phase throughput. x-load batch + cvt + swizzled LDS write
// + barrier, repeated P1_REPS times over rotating slices. dur/24 = per-slice
// staging cost in steady state.
// ---------------------------------------------------------------------------
__global__ __launch_bounds__(256, 4) void probe_stage(
        const float* __restrict__ x, float* __restrict__ dummy) {
    __shared__ char lds[XBYTES];
    const int bid = blockIdx.x;
    const int t = threadIdx.x;
    float chk = 0.f;
    #pragma unroll 1
    for (int r = 0; r < P1_REPS; ++r) {
        const int sb = (bid + 61 * r) & 1023;
        const int b = sb >> 1, h = sb & 1;
        const char* slice = (const char*)(x + (size_t)b * LROW + h * 16384);
        float4 va[8], vb[8], vt;
        #pragma unroll
        for (int i = 0; i < 8; ++i)
            va[i] = *reinterpret_cast<const float4*>(slice + (i * 256 + t) * 16);
        #pragma unroll
        for (int i = 0; i < 8; ++i)
            vb[i] = *reinterpret_cast<const float4*>(slice + ((i + 8) * 256 + t) * 16);
        {
            const char* tsrc = h ? (const char*)(x + (size_t)b * LROW) : slice + 65536;
            if (t < 64) vt = *reinterpret_cast<const float4*>(tsrc + t * 16);
        }
        #pragma unroll
        for (int i = 0; i < 8; ++i)
            *reinterpret_cast<ushort4*>(lds + xsw((i * 256 + t) * 8)) = cvt4(va[i]);
        #pragma unroll
        for (int i = 0; i < 8; ++i)
            *reinterpret_cast<ushort4*>(lds + xsw(((i + 8) * 256 + t) * 8)) = cvt4(vb[i]);
        if (t < 64)
            *reinterpret_cast<ushort4*>(lds + xsw((4096 + t) * 8)) = cvt4(vt);
        __syncthreads();
        // consume one word so no write set is dead (keeps loads+writes live)
        int idx = ((t * 132 + r * 68) % 33280) & ~3;
        chk += *reinterpret_cast<const float*>(lds + idx);
        __syncthreads();
    }
    dummy[bid * 256 + t] = chk;
}

// ---------------------------------------------------------------------------
// PROBE 2: compute-phase throughput. Stage once, then P2_REPS full passes of
// {B-loads from L2 (lookahead named sets) + ds_read_b128 A-fragments + MFMA},
// rotating the ntile set per rep. dur/20 = per-pass compute cost.
// ---------------------------------------------------------------------------
__global__ __launch_bounds__(256, 4) void probe_compute(
        const float* __restrict__ x, const unsigned short* __restrict__ wfrag,
        float* __restrict__ dummy) {
    __shared__ char lds[XBYTES];
    const int bid = blockIdx.x;
    const int b = bid >> 1;
    const int h = bid & 1;
    const int t = threadIdx.x;
    const int lane = t & 63;
    const int wv = t >> 6;
    const int rl = lane & 15;
    const int gl = lane >> 4;

    const char* slice = (const char*)(x + (size_t)b * LROW + h * 16384);
    {
        float4 va[8], vb[8], vt;
        #pragma unroll
        for (int i = 0; i < 8; ++i)
            va[i] = *reinterpret_cast<const float4*>(slice + (i * 256 + t) * 16);
        #pragma unroll
        for (int i = 0; i < 8; ++i)
            vb[i] = *reinterpret_cast<const float4*>(slice + ((i + 8) * 256 + t) * 16);
        {
            const char* tsrc = h ? (const char*)(x + (size_t)b * LROW) : slice + 65536;
            if (t < 64) vt = *reinterpret_cast<const float4*>(tsrc + t * 16);
        }
        #pragma unroll
        for (int i = 0; i < 8; ++i)
            *reinterpret_cast<ushort4*>(lds + xsw((i * 256 + t) * 8)) = cvt4(va[i]);
        #pragma unroll
        for (int i = 0; i < 8; ++i)
            *reinterpret_cast<ushort4*>(lds + xsw(((i + 8) * 256 + t) * 8)) = cvt4(vb[i]);
        if (t < 64)
            *reinterpret_cast<ushort4*>(lds + xsw((4096 + t) * 8)) = cvt4(vt);
    }
    __syncthreads();

    f32x4 acc[4][2];
    #pragma unroll
    for (int mi = 0; mi < 4; ++mi)
        #pragma unroll
        for (int ni = 0; ni < 2; ++ni)
            acc[mi][ni] = (f32x4){0.f, 0.f, 0.f, 0.f};

    #pragma unroll 1
    for (int r = 0; r < P2_REPS; ++r) {
        const int nt0r = ((wv + r) & 3) * 2;
        short8 bqA[4][2], bqB[4][2];
        auto loadq = [&](short8 (&dst)[4][2], int q) {
            #pragma unroll
            for (int kkq = 0; kkq < 4; ++kkq)
                #pragma unroll
                for (int ni = 0; ni < 2; ++ni)
                    dst[kkq][ni] = *reinterpret_cast<const short8*>(
                        wfrag + ((size_t)(((nt0r + ni) * 16 + q * 4 + kkq) * 64 + lane)) * 8);
        };
        auto computeq = [&](short8 (&bq)[4][2], int q) {
            #pragma unroll
            for (int kkq = 0; kkq < 4; ++kkq) {
                const int kb = (q * 4 + kkq) * 64 + gl * 16;
                short8 af[4];
                #pragma unroll
                for (int mi = 0; mi < 4; ++mi)
                    af[mi] = *reinterpret_cast<const short8*>(
                        lds + xsw((mi * 16 + rl) * 512 + kb));
                #pragma unroll
                for (int mi = 0; mi < 4; ++mi) {
                    acc[mi][0] = __builtin_amdgcn_mfma_f32_16x16x32_bf16(af[mi], bq[kkq][0], acc[mi][0], 0, 0, 0);
                    acc[mi][1] = __builtin_amdgcn_mfma_f32_16x16x32_bf16(af[mi], bq[kkq][1], acc[mi][1], 0, 0, 0);
                }
            }
        };
        loadq(bqA, 0);
        loadq(bqB, 1);
        computeq(bqA, 0);
        loadq(bqA, 2);
        computeq(bqB, 1);
        loadq(bqB, 3);
        computeq(bqA, 2);
        computeq(bqB, 3);
    }

    float s = 0.f;
    #pragma unroll
    for (int mi = 0; mi < 4; ++mi)
        #pragma unroll
        for (int ni = 0; ni < 2; ++ni)
            #pragma unroll
            for (int rr = 0; rr < 4; ++rr) s += acc[mi][ni][rr];
    dummy[262144 + bid * 256 + t] = s;
}

// ---------------------------------------------------------------------------
// Main (unchanged from round 9 — produces the validated output)
// ---------------------------------------------------------------------------
__global__ __launch_bounds__(256, 4) void main_kernel(
        const float* __restrict__ x,
        const unsigned short* __restrict__ wfrag,
        float* __restrict__ out) {
    __shared__ char lds[XBYTES];
    const int bid = blockIdx.x;
    const int b = bid >> 1;
    const int h = bid & 1;
    const int t = threadIdx.x;
    const int lane = t & 63;
    const int wv = t >> 6;          // 0..3
    const int rl = lane & 15;
    const int gl = lane >> 4;
    const int nt0 = wv * 2;         // this wave's first ntile

    const char* slice = (const char*)(x + (size_t)b * LROW + h * 16384);

    float4 va[8], vb[8], vt;
    #pragma unroll
    for (int i = 0; i < 8; ++i)
        va[i] = *reinterpret_cast<const float4*>(slice + (i * 256 + t) * 16);
    #pragma unroll
    for (int i = 0; i < 8; ++i)
        vb[i] = *reinterpret_cast<const float4*>(slice + ((i + 8) * 256 + t) * 16);
    {
        const char* tsrc = h ? (const char*)(x + (size_t)b * LROW)
                             : slice + 65536;
        if (t < 64) vt = *reinterpret_cast<const float4*>(tsrc + t * 16);
    }

    short8 bqA[4][2], bqB[4][2];
    auto loadq = [&](short8 (&dst)[4][2], int q) {
        #pragma unroll
        for (int kkq = 0; kkq < 4; ++kkq)
            #pragma unroll
            for (int ni = 0; ni < 2; ++ni)
                dst[kkq][ni] = *reinterpret_cast<const short8*>(
                    wfrag + ((size_t)(((nt0 + ni) * 16 + q * 4 + kkq) * 64 + lane)) * 8);
    };
    loadq(bqA, 0);

    #pragma unroll
    for (int i = 0; i < 8; ++i)
        *reinterpret_cast<ushort4*>(lds + xsw((i * 256 + t) * 8)) = cvt4(va[i]);
    #pragma unroll
    for (int i = 0; i < 8; ++i)
        *reinterpret_cast<ushort4*>(lds + xsw(((i + 8) * 256 + t) * 8)) = cvt4(vb[i]);
    if (t < 64)
        *reinterpret_cast<ushort4*>(lds + xsw((4096 + t) * 8)) = cvt4(vt);

    f32x4 acc[4][2];
    #pragma unroll
    for (int mi = 0; mi < 4; ++mi)
        #pragma unroll
        for (int ni = 0; ni < 2; ++ni)
            acc[mi][ni] = (f32x4){0.f, 0.f, 0.f, 0.f};

    auto compute = [&](short8 (&bq)[4][2], int q) {
        #pragma unroll
        for (int kkq = 0; kkq < 4; ++kkq) {
            const int kb = (q * 4 + kkq) * 64 + gl * 16;   // byte offset in k
            short8 af[4];
            #pragma unroll
            for (int mi = 0; mi < 4; ++mi)
                af[mi] = *reinterpret_cast<const short8*>(
                    lds + xsw((mi * 16 + rl) * 512 + kb));
            #pragma unroll
            for (int mi = 0; mi < 4; ++mi) {
                acc[mi][0] = __builtin_amdgcn_mfma_f32_16x16x32_bf16(af[mi], bq[kkq][0], acc[mi][0], 0, 0, 0);
                acc[mi][1] = __builtin_amdgcn_mfma_f32_16x16x32_bf16(af[mi], bq[kkq][1], acc[mi][1], 0, 0, 0);
            }
        }
    };

    loadq(bqB, 1);          // in flight during q0 compute
    __syncthreads();        // x slice visible to all waves
    compute(bqA, 0);
    loadq(bqA, 2);          // in flight during q1 compute
    compute(bqB, 1);
    loadq(bqB, 3);          // in flight during q2 compute
    compute(bqA, 2);
    compute(bqB, 3);

    #pragma unroll
    for (int ni = 0; ni < 2; ++ni) {
        float s = 0.f;
        #pragma unroll
        for (int mi = 0; mi < 4; ++mi) {
            #pragma unroll
            for (int r = 0; r < 4; ++r) {
                float p = acc[mi][ni][r];
                float qq = p * p;
                qq += __shfl_xor(qq, 1);
                qq += __shfl_xor(qq, 2);
                qq += __shfl_xor(qq, 4);
                s += sqrtf(qq);
            }
        }
        s += __shfl_xor(s, 16);
        s += __shfl_xor(s, 32);
        if (lane < 16 && (lane & 7) == 0) {
            int c = (wv * 32 + ni * 16 + lane) >> 3;
            atomicAdd(&out[b * NUM_C + c], s * (1.0f / 128.0f));
        }
    }
}

extern "C" void kernel_launch(void* const* d_in, const int* in_sizes, int n_in,
                              void* d_out, int out_size, void* d_ws, size_t ws_size,
                              hipStream_t stream) {
    (void)in_sizes; (void)n_in; (void)ws_size; (void)out_size;
    const float* x      = (const float*)d_in[0];
    const float* weight = (const float*)d_in[1];
    float* out = (float*)d_out;
    unsigned short* wfrag = (unsigned short*)d_ws;              // 128 KiB
    float* dummy = (float*)((char*)d_ws + (64u << 20));         // probe scratch

    prep_kernel<<<16, 256, 0, stream>>>(weight, wfrag, out);
    probe_stage<<<1024, 256, 0, stream>>>(x, dummy);
    probe_compute<<<1024, 256, 0, stream>>>(x, wfrag, dummy);
    main_kernel<<<1024, 256, 0, stream>>>(x, wfrag, out);
}

// Round 11
// 767.439 us; speedup vs baseline: 1.3286x; 1.3286x over previous
//
#include <hip/hip_runtime.h>
#include <hip/hip_bf16.h>

#define NUM_C  16
#define NUM_D  8
#define RECEPT 512
#define LROW   32768
#define EPS_V  1e-4f

// per-block x slice: 64 windows * 256 stride + 256 overlap = 16640 bf16
// = 33280 B; +headroom for xsw (sets bits 4-6) -> 33536
#define XBYTES 33536
#define PROBE_REPS 10

typedef __attribute__((ext_vector_type(8))) short short8;
typedef __attribute__((ext_vector_type(4))) float f32x4;

__device__ __forceinline__ unsigned short f2bf(float f) {
    unsigned int u = __builtin_bit_cast(unsigned int, f);
    u += 0x7fffu + ((u >> 16) & 1u);   // round-to-nearest-even
    return (unsigned short)(u >> 16);
}

// XOR swizzle on byte address in the bf16 x LDS slice (involution; applied on
// both staging writes and A-fragment reads; breaks the 512B window stride).
__device__ __forceinline__ int xsw(int a) { return a ^ (((a >> 9) & 7) << 4); }

__device__ __forceinline__ ushort4 cvt4(float4 v) {
    ushort4 h;
    h.x = f2bf(v.x); h.y = f2bf(v.y); h.z = f2bf(v.z); h.w = f2bf(v.w);
    return h;
}

// ---------------------------------------------------------------------------
// Prep (16 blocks x 256 thr): per c: G = W W^T + eps I ; chol; Wt = L^{-1} W ;
// store Wt bf16 in MFMA B-fragment order:
//   wfrag[ntile(8)][kk(16)][lane(64)][j(8)]
//   value = Wt[cd = ntile*16 + (lane&15)][r = kk*32 + (lane>>4)*8 + j]
// Also zeroes d_out.
// ---------------------------------------------------------------------------
__global__ void prep_kernel(const float* __restrict__ weight,
                            unsigned short* __restrict__ wfrag,
                            float* __restrict__ out) {
    __shared__ float Wc[NUM_D * RECEPT];
    __shared__ float G[NUM_D][NUM_D];
    __shared__ float Lm[NUM_D][NUM_D];
    const int c = blockIdx.x;
    const int t = threadIdx.x;  // 256 threads

    out[c * 256 + t] = 0.f;
    out[c * 256 + t + 4096] = 0.f;

    const float4* wsrc4 = reinterpret_cast<const float4*>(
        weight + (size_t)c * NUM_D * RECEPT);
    float4* Wc4 = reinterpret_cast<float4*>(Wc);
    #pragma unroll
    for (int i = 0; i < 4; ++i) Wc4[t + i * 256] = wsrc4[t + i * 256];
    __syncthreads();

    if (t < 64) {
        int d = t >> 3, e = t & 7;
        const float4* wd4 = reinterpret_cast<const float4*>(&Wc[d * RECEPT]);
        const float4* we4 = reinterpret_cast<const float4*>(&Wc[e * RECEPT]);
        float s = 0.f;
        #pragma unroll 4
        for (int r4 = 0; r4 < RECEPT / 4; ++r4) {
            float4 a = wd4[r4], bb = we4[r4];
            s += a.x * bb.x + a.y * bb.y + a.z * bb.z + a.w * bb.w;
        }
        if (d == e) s += EPS_V;
        G[d][e] = s;
    }
    __syncthreads();
    if (t == 0) {
        for (int i = 0; i < NUM_D; ++i) {
            float diag = G[i][i];
            for (int k = 0; k < i; ++k) diag -= Lm[i][k] * Lm[i][k];
            float di = sqrtf(diag);
            Lm[i][i] = di;
            float inv = 1.f / di;
            for (int jj = i + 1; jj < NUM_D; ++jj) {
                float s = G[jj][i];
                for (int k = 0; k < i; ++k) s -= Lm[jj][k] * Lm[i][k];
                Lm[jj][i] = s * inv;
            }
        }
    }
    __syncthreads();
    for (int r = t; r < RECEPT; r += 256) {
        float y[NUM_D];
        for (int d = 0; d < NUM_D; ++d) {
            float s = Wc[d * RECEPT + r];
            for (int k = 0; k < d; ++k) s -= Lm[d][k] * y[k];
            y[d] = s / Lm[d][d];
        }
        const int kk = r >> 5;          // 0..15
        const int g  = (r >> 3) & 3;    // k-group within 32
        const int j  = r & 7;
        for (int d = 0; d < NUM_D; ++d) {
            int cd = c * NUM_D + d;
            int ntile = cd >> 4;
            int nl = cd & 15;
            int lane = g * 16 + nl;
            int idx = (((ntile * 16 + kk) * 64) + lane) * 8 + j;
            wfrag[idx] = f2bf(y[d]);
        }
    }
}

// ---------------------------------------------------------------------------
// One full block-tile: stage slice sb, compute 64 win x 128 cd, reduce, emit.
// ALL registers named; no lambdas; no array passed anywhere -> SROA-safe.
// ---------------------------------------------------------------------------
__device__ __forceinline__ void run_block(
        const float* __restrict__ x,
        const unsigned short* __restrict__ wfrag,
        float* __restrict__ outp,
        char* lds, int sb, int t) {
    const int b = sb >> 1;
    const int h = sb & 1;
    const int lane = t & 63;
    const int wv = t >> 6;          // 0..3
    const int rl = lane & 15;
    const int gl = lane >> 4;
    const int nt0 = wv * 2;         // this wave's first ntile

    const char* slice = (const char*)(x + (size_t)b * LROW + h * 16384);

    // ---- staging: 17 float4 issued as one batch, then cvt+swizzled write ----
    float4 va[8], vb[8], vt;
    #pragma unroll
    for (int i = 0; i < 8; ++i)
        va[i] = *reinterpret_cast<const float4*>(slice + (i * 256 + t) * 16);
    #pragma unroll
    for (int i = 0; i < 8; ++i)
        vb[i] = *reinterpret_cast<const float4*>(slice + ((i + 8) * 256 + t) * 16);
    {
        const char* tsrc = h ? (const char*)(x + (size_t)b * LROW)
                             : slice + 65536;
        if (t < 64) vt = *reinterpret_cast<const float4*>(tsrc + t * 16);
    }
    #pragma unroll
    for (int i = 0; i < 8; ++i)
        *reinterpret_cast<ushort4*>(lds + xsw((i * 256 + t) * 8)) = cvt4(va[i]);
    #pragma unroll
    for (int i = 0; i < 8; ++i)
        *reinterpret_cast<ushort4*>(lds + xsw(((i + 8) * 256 + t) * 8)) = cvt4(vb[i]);
    if (t < 64)
        *reinterpret_cast<ushort4*>(lds + xsw((4096 + t) * 8)) = cvt4(vt);

    f32x4 a00 = {0,0,0,0}, a01 = {0,0,0,0};
    f32x4 a10 = {0,0,0,0}, a11 = {0,0,0,0};
    f32x4 a20 = {0,0,0,0}, a21 = {0,0,0,0};
    f32x4 a30 = {0,0,0,0}, a31 = {0,0,0,0};

    __syncthreads();        // x slice visible to all waves

#define BLOAD(dst_, q_, kkq_, ni_) \
    dst_ = *reinterpret_cast<const short8*>( \
        wfrag + ((size_t)(((nt0 + (ni_)) * 16 + (q_) * 4 + (kkq_)) * 64 + lane)) * 8)
#define AREAD(dst_, mi_, q_, kkq_) \
    dst_ = *reinterpret_cast<const short8*>( \
        lds + xsw(((mi_) * 16 + rl) * 512 + ((q_) * 4 + (kkq_)) * 64 + gl * 16))
#define MF(acc_, af_, bf_) \
    acc_ = __builtin_amdgcn_mfma_f32_16x16x32_bf16(af_, bf_, acc_, 0, 0, 0)

#define KSTEP(q_, kkq_, bA_, bB_) { \
    short8 af0, af1, af2, af3; \
    AREAD(af0, 0, q_, kkq_); AREAD(af1, 1, q_, kkq_); \
    AREAD(af2, 2, q_, kkq_); AREAD(af3, 3, q_, kkq_); \
    MF(a00, af0, bA_); MF(a01, af0, bB_); \
    MF(a10, af1, bA_); MF(a11, af1, bB_); \
    MF(a20, af2, bA_); MF(a21, af2, bB_); \
    MF(a30, af3, bA_); MF(a31, af3, bB_); }

#define QUARTER(q_) { \
    short8 b0a, b0b, b1a, b1b, b2a, b2b, b3a, b3b; \
    BLOAD(b0a, q_, 0, 0); BLOAD(b0b, q_, 0, 1); \
    BLOAD(b1a, q_, 1, 0); BLOAD(b1b, q_, 1, 1); \
    BLOAD(b2a, q_, 2, 0); BLOAD(b2b, q_, 2, 1); \
    BLOAD(b3a, q_, 3, 0); BLOAD(b3b, q_, 3, 1); \
    KSTEP(q_, 0, b0a, b0b); \
    KSTEP(q_, 1, b1a, b1b); \
    KSTEP(q_, 2, b2a, b2b); \
    KSTEP(q_, 3, b3a, b3b); }

    QUARTER(0)
    QUARTER(1)
    QUARTER(2)
    QUARTER(3)

#undef QUARTER
#undef KSTEP
#undef MF
#undef AREAD
#undef BLOAD

    // epilogue: q = sum over 8 d-columns of P^2 (lane bits 0..2), sqrt,
    // sum over this block's 64 windows, atomics (mean weight 1/128).
#define SQSUM(s_, A_) { \
    _Pragma("unroll") \
    for (int r = 0; r < 4; ++r) { \
        float p = (A_)[r]; float qq = p * p; \
        qq += __shfl_xor(qq, 1); \
        qq += __shfl_xor(qq, 2); \
        qq += __shfl_xor(qq, 4); \
        s_ += sqrtf(qq); } }

    float s0 = 0.f, s1 = 0.f;
    SQSUM(s0, a00) SQSUM(s0, a10) SQSUM(s0, a20) SQSUM(s0, a30)
    SQSUM(s1, a01) SQSUM(s1, a11) SQSUM(s1, a21) SQSUM(s1, a31)
#undef SQSUM
    s0 += __shfl_xor(s0, 16); s0 += __shfl_xor(s0, 32);
    s1 += __shfl_xor(s1, 16); s1 += __shfl_xor(s1, 32);
    if (lane < 16 && (lane & 7) == 0) {
        int c0 = (wv * 32 + lane) >> 3;
        atomicAdd(&outp[b * NUM_C + c0], s0 * (1.0f / 128.0f));
        atomicAdd(&outp[b * NUM_C + c0 + 2], s1 * (1.0f / 128.0f));
    }
    __syncthreads();        // protect LDS for any following reuse
}

// ---------------------------------------------------------------------------
// Main: 1024 blocks x 256 thr (4 waves), one generation (4 blocks/CU).
// ---------------------------------------------------------------------------
__global__ __launch_bounds__(256, 4) void main_kernel(
        const float* __restrict__ x,
        const unsigned short* __restrict__ wfrag,
        float* __restrict__ out) {
    __shared__ char lds[XBYTES];
    run_block(x, wfrag, out, lds, blockIdx.x, threadIdx.x);
}

// ---------------------------------------------------------------------------
// PROBE: the exact same body x10 with rotating slices -> surfaces above the
// harness fill floor with full counters. Writes to scratch, not d_out.
// ---------------------------------------------------------------------------
__global__ __launch_bounds__(256, 4) void probe_main(
        const float* __restrict__ x,
        const unsigned short* __restrict__ wfrag,
        float* __restrict__ dummy) {
    __shared__ char lds[XBYTES];
    #pragma unroll 1
    for (int r = 0; r < PROBE_REPS; ++r) {
        int sb = (blockIdx.x + 331 * r) & 1023;
        run_block(x, wfrag, dummy, lds, sb, threadIdx.x);
    }
}

extern "C" void kernel_launch(void* const* d_in, const int* in_sizes, int n_in,
                              void* d_out, int out_size, void* d_ws, size_t ws_size,
                              hipStream_t stream) {
    (void)in_sizes; (void)n_in; (void)ws_size; (void)out_size;
    const float* x      = (const float*)d_in[0];
    const float* weight = (const float*)d_in[1];
    float* out = (float*)d_out;
    unsigned short* wfrag = (unsigned short*)d_ws;              // 128 KiB
    float* dummy = (float*)((char*)d_ws + (64u << 20));         // probe scratch

    prep_kernel<<<16, 256, 0, stream>>>(weight, wfrag, out);
    probe_main<<<1024, 256, 0, stream>>>(x, wfrag, dummy);
    main_kernel<<<1024, 256, 0, stream>>>(x, wfrag, out);
}

// Round 13
// 59.973 us; speedup vs baseline: 17.0019x; 12.7965x over previous
//
#include <hip/hip_runtime.h>
#include <hip/hip_bf16.h>

#define NUM_C  16
#define NUM_D  8
#define RECEPT 512
#define LROW   32768
#define EPS_V  1e-4f

// per-block x slice: 64 windows * 256 stride + 256 overlap = 16640 bf16
// = 33280 B; +headroom for xsw (sets bits 4-6) -> 33536
#define XBYTES 33536

typedef __attribute__((ext_vector_type(8))) short short8;
typedef __attribute__((ext_vector_type(4))) float f32x4;

__device__ __forceinline__ unsigned short f2bf(float f) {
    unsigned int u = __builtin_bit_cast(unsigned int, f);
    u += 0x7fffu + ((u >> 16) & 1u);   // round-to-nearest-even
    return (unsigned short)(u >> 16);
}

// XOR swizzle on byte address in the bf16 x LDS slice (involution; applied on
// both staging writes and A-fragment reads; breaks the 512B window stride).
__device__ __forceinline__ int xsw(int a) { return a ^ (((a >> 9) & 7) << 4); }

__device__ __forceinline__ ushort4 cvt4(f32x4 v) {
    ushort4 h;
    h.x = f2bf(v[0]); h.y = f2bf(v[1]); h.z = f2bf(v[2]); h.w = f2bf(v[3]);
    return h;
}

// ---------------------------------------------------------------------------
// Prep (16 blocks x 256 thr): per c: G = W W^T + eps I ; chol; Wt = L^{-1} W ;
// store Wt bf16 in MFMA B-fragment order:
//   wfrag[ntile(8)][kk(16)][lane(64)][j(8)]
//   value = Wt[cd = ntile*16 + (lane&15)][r = kk*32 + (lane>>4)*8 + j]
// Also zeroes d_out.
// ---------------------------------------------------------------------------
__global__ void prep_kernel(const float* __restrict__ weight,
                            unsigned short* __restrict__ wfrag,
                            float* __restrict__ out) {
    __shared__ float Wc[NUM_D * RECEPT];
    __shared__ float G[NUM_D][NUM_D];
    __shared__ float Lm[NUM_D][NUM_D];
    const int c = blockIdx.x;
    const int t = threadIdx.x;  // 256 threads

    out[c * 256 + t] = 0.f;
    out[c * 256 + t + 4096] = 0.f;

    const float4* wsrc4 = reinterpret_cast<const float4*>(
        weight + (size_t)c * NUM_D * RECEPT);
    float4* Wc4 = reinterpret_cast<float4*>(Wc);
    #pragma unroll
    for (int i = 0; i < 4; ++i) Wc4[t + i * 256] = wsrc4[t + i * 256];
    __syncthreads();

    if (t < 64) {
        int d = t >> 3, e = t & 7;
        const float4* wd4 = reinterpret_cast<const float4*>(&Wc[d * RECEPT]);
        const float4* we4 = reinterpret_cast<const float4*>(&Wc[e * RECEPT]);
        float s = 0.f;
        #pragma unroll 4
        for (int r4 = 0; r4 < RECEPT / 4; ++r4) {
            float4 a = wd4[r4], bb = we4[r4];
            s += a.x * bb.x + a.y * bb.y + a.z * bb.z + a.w * bb.w;
        }
        if (d == e) s += EPS_V;
        G[d][e] = s;
    }
    __syncthreads();
    if (t == 0) {
        for (int i = 0; i < NUM_D; ++i) {
            float diag = G[i][i];
            for (int k = 0; k < i; ++k) diag -= Lm[i][k] * Lm[i][k];
            float di = sqrtf(diag);
            Lm[i][i] = di;
            float inv = 1.f / di;
            for (int jj = i + 1; jj < NUM_D; ++jj) {
                float s = G[jj][i];
                for (int k = 0; k < i; ++k) s -= Lm[jj][k] * Lm[i][k];
                Lm[jj][i] = s * inv;
            }
        }
    }
    __syncthreads();
    for (int r = t; r < RECEPT; r += 256) {
        float y[NUM_D];
        for (int d = 0; d < NUM_D; ++d) {
            float s = Wc[d * RECEPT + r];
            for (int k = 0; k < d; ++k) s -= Lm[d][k] * y[k];
            y[d] = s / Lm[d][d];
        }
        const int kk = r >> 5;          // 0..15
        const int g  = (r >> 3) & 3;    // k-group within 32
        const int j  = r & 7;
        for (int d = 0; d < NUM_D; ++d) {
            int cd = c * NUM_D + d;
            int ntile = cd >> 4;
            int nl = cd & 15;
            int lane = g * 16 + nl;
            int idx = (((ntile * 16 + kk) * 64) + lane) * 8 + j;
            wfrag[idx] = f2bf(y[d]);
        }
    }
}

// ---------------------------------------------------------------------------
// Main: 1024 blocks (b = bid>>1, half h = bid&1) x 256 thr (4 waves), one
// generation (4 blocks/CU, 16 waves/CU). x staged via NON-TEMPORAL loads
// (evict-first in L2 -> wfrag stays L2-resident; B-loads become L2 hits) in
// two 8-deep batches (peak ~50 VGPR, no spill at the (256,4) 128-reg cap).
// Compute: named-register straight-line MFMA (R11 body, spill-proof).
// ---------------------------------------------------------------------------
__global__ __launch_bounds__(256, 4) void main_kernel(
        const float* __restrict__ x,
        const unsigned short* __restrict__ wfrag,
        float* __restrict__ out) {
    __shared__ char lds[XBYTES];
    const int bid = blockIdx.x;
    const int b = bid >> 1;
    const int h = bid & 1;
    const int t = threadIdx.x;
    const int lane = t & 63;
    const int wv = t >> 6;          // 0..3
    const int rl = lane & 15;
    const int gl = lane >> 4;
    const int nt0 = wv * 2;         // this wave's first ntile

    const char* slice = (const char*)(x + (size_t)b * LROW + h * 16384);

    // ---- staging batch 1: 8 nt loads + tail, then cvt + swizzled writes ----
    {
        f32x4 va[8], vt;
        #pragma unroll
        for (int i = 0; i < 8; ++i)
            va[i] = __builtin_nontemporal_load(
                reinterpret_cast<const f32x4*>(slice + (i * 256 + t) * 16));
        const char* tsrc = h ? (const char*)(x + (size_t)b * LROW)
                             : slice + 65536;
        if (t < 64)
            vt = __builtin_nontemporal_load(
                reinterpret_cast<const f32x4*>(tsrc + t * 16));
        #pragma unroll
        for (int i = 0; i < 8; ++i)
            *reinterpret_cast<ushort4*>(lds + xsw((i * 256 + t) * 8)) = cvt4(va[i]);
        if (t < 64)
            *reinterpret_cast<ushort4*>(lds + xsw((4096 + t) * 8)) = cvt4(vt);
    }
    // ---- staging batch 2: 8 nt loads, then cvt + swizzled writes ----
    {
        f32x4 vb[8];
        #pragma unroll
        for (int i = 0; i < 8; ++i)
            vb[i] = __builtin_nontemporal_load(
                reinterpret_cast<const f32x4*>(slice + ((i + 8) * 256 + t) * 16));
        #pragma unroll
        for (int i = 0; i < 8; ++i)
            *reinterpret_cast<ushort4*>(lds + xsw(((i + 8) * 256 + t) * 8)) = cvt4(vb[i]);
    }

    f32x4 a00 = {0,0,0,0}, a01 = {0,0,0,0};
    f32x4 a10 = {0,0,0,0}, a11 = {0,0,0,0};
    f32x4 a20 = {0,0,0,0}, a21 = {0,0,0,0};
    f32x4 a30 = {0,0,0,0}, a31 = {0,0,0,0};

    __syncthreads();        // x slice visible to all waves

#define BLOAD(dst_, q_, kkq_, ni_) \
    dst_ = *reinterpret_cast<const short8*>( \
        wfrag + ((size_t)(((nt0 + (ni_)) * 16 + (q_) * 4 + (kkq_)) * 64 + lane)) * 8)
#define AREAD(dst_, mi_, q_, kkq_) \
    dst_ = *reinterpret_cast<const short8*>( \
        lds + xsw(((mi_) * 16 + rl) * 512 + ((q_) * 4 + (kkq_)) * 64 + gl * 16))
#define MF(acc_, af_, bf_) \
    acc_ = __builtin_amdgcn_mfma_f32_16x16x32_bf16(af_, bf_, acc_, 0, 0, 0)

#define KSTEP(q_, kkq_, bA_, bB_) { \
    short8 af0, af1, af2, af3; \
    AREAD(af0, 0, q_, kkq_); AREAD(af1, 1, q_, kkq_); \
    AREAD(af2, 2, q_, kkq_); AREAD(af3, 3, q_, kkq_); \
    MF(a00, af0, bA_); MF(a01, af0, bB_); \
    MF(a10, af1, bA_); MF(a11, af1, bB_); \
    MF(a20, af2, bA_); MF(a21, af2, bB_); \
    MF(a30, af3, bA_); MF(a31, af3, bB_); }

#define QUARTER(q_) { \
    short8 b0a, b0b, b1a, b1b, b2a, b2b, b3a, b3b; \
    BLOAD(b0a, q_, 0, 0); BLOAD(b0b, q_, 0, 1); \
    BLOAD(b1a, q_, 1, 0); BLOAD(b1b, q_, 1, 1); \
    BLOAD(b2a, q_, 2, 0); BLOAD(b2b, q_, 2, 1); \
    BLOAD(b3a, q_, 3, 0); BLOAD(b3b, q_, 3, 1); \
    KSTEP(q_, 0, b0a, b0b); \
    KSTEP(q_, 1, b1a, b1b); \
    KSTEP(q_, 2, b2a, b2b); \
    KSTEP(q_, 3, b3a, b3b); }

    QUARTER(0)
    QUARTER(1)
    QUARTER(2)
    QUARTER(3)

#undef QUARTER
#undef KSTEP
#undef MF
#undef AREAD
#undef BLOAD

    // epilogue: q = sum over 8 d-columns of P^2 (lane bits 0..2), sqrt,
    // sum over this block's 64 windows, atomics (mean weight 1/128).
#define SQSUM(s_, A_) { \
    _Pragma("unroll") \
    for (int r = 0; r < 4; ++r) { \
        float p = (A_)[r]; float qq = p * p; \
        qq += __shfl_xor(qq, 1); \
        qq += __shfl_xor(qq, 2); \
        qq += __shfl_xor(qq, 4); \
        s_ += sqrtf(qq); } }

    float s0 = 0.f, s1 = 0.f;
    SQSUM(s0, a00) SQSUM(s0, a10) SQSUM(s0, a20) SQSUM(s0, a30)
    SQSUM(s1, a01) SQSUM(s1, a11) SQSUM(s1, a21) SQSUM(s1, a31)
#undef SQSUM
    s0 += __shfl_xor(s0, 16); s0 += __shfl_xor(s0, 32);
    s1 += __shfl_xor(s1, 16); s1 += __shfl_xor(s1, 32);
    if (lane < 16 && (lane & 7) == 0) {
        int c0 = (wv * 32 + lane) >> 3;
        atomicAdd(&out[b * NUM_C + c0], s0 * (1.0f / 128.0f));
        atomicAdd(&out[b * NUM_C + c0 + 2], s1 * (1.0f / 128.0f));
    }
}

extern "C" void kernel_launch(void* const* d_in, const int* in_sizes, int n_in,
                              void* d_out, int out_size, void* d_ws, size_t ws_size,
                              hipStream_t stream) {
    (void)in_sizes; (void)n_in; (void)ws_size; (void)out_size;
    const float* x      = (const float*)d_in[0];
    const float* weight = (const float*)d_in[1];
    float* out = (float*)d_out;
    unsigned short* wfrag = (unsigned short*)d_ws;   // needs 128 KiB scratch

    prep_kernel<<<16, 256, 0, stream>>>(weight, wfrag, out);
    main_kernel<<<1024, 256, 0, stream>>>(x, wfrag, out);
}

// Round 14
// 59.220 us; speedup vs baseline: 17.2181x; 1.0127x over previous
//
#include <hip/hip_runtime.h>
#include <hip/hip_bf16.h>

#define NUM_C  16
#define NUM_D  8
#define RECEPT 512
#define LROW   32768
#define EPS_V  1e-4f

// per-block x slice: 64 windows * 256 stride + 256 overlap = 16640 bf16
// = 33280 B; +headroom for xsw (sets bits 4-6) -> 33536
#define XBYTES 33536

typedef __attribute__((ext_vector_type(8))) short short8;
typedef __attribute__((ext_vector_type(4))) float f32x4;

__device__ __forceinline__ unsigned short f2bf(float f) {
    unsigned int u = __builtin_bit_cast(unsigned int, f);
    u += 0x7fffu + ((u >> 16) & 1u);   // round-to-nearest-even
    return (unsigned short)(u >> 16);
}

// XOR swizzle on byte address in the bf16 x LDS slice (involution; applied on
// both staging writes and A-fragment reads; breaks the 512B window stride).
__device__ __forceinline__ int xsw(int a) { return a ^ (((a >> 9) & 7) << 4); }

__device__ __forceinline__ ushort4 cvt4(f32x4 v) {
    ushort4 h;
    h.x = f2bf(v[0]); h.y = f2bf(v[1]); h.z = f2bf(v[2]); h.w = f2bf(v[3]);
    return h;
}

// ---------------------------------------------------------------------------
// Prep (16 blocks x 256 thr): per c: G = W W^T + eps I ; chol; Wt = L^{-1} W ;
// store Wt bf16 in MFMA B-fragment order:
//   wfrag[ntile(8)][kk(16)][lane(64)][j(8)]
//   value = Wt[cd = ntile*16 + (lane&15)][r = kk*32 + (lane>>4)*8 + j]
// Also zeroes d_out.
// ---------------------------------------------------------------------------
__global__ void prep_kernel(const float* __restrict__ weight,
                            unsigned short* __restrict__ wfrag,
                            float* __restrict__ out) {
    __shared__ float Wc[NUM_D * RECEPT];
    __shared__ float G[NUM_D][NUM_D];
    __shared__ float Lm[NUM_D][NUM_D];
    const int c = blockIdx.x;
    const int t = threadIdx.x;  // 256 threads

    out[c * 256 + t] = 0.f;
    out[c * 256 + t + 4096] = 0.f;

    const float4* wsrc4 = reinterpret_cast<const float4*>(
        weight + (size_t)c * NUM_D * RECEPT);
    float4* Wc4 = reinterpret_cast<float4*>(Wc);
    #pragma unroll
    for (int i = 0; i < 4; ++i) Wc4[t + i * 256] = wsrc4[t + i * 256];
    __syncthreads();

    if (t < 64) {
        int d = t >> 3, e = t & 7;
        const float4* wd4 = reinterpret_cast<const float4*>(&Wc[d * RECEPT]);
        const float4* we4 = reinterpret_cast<const float4*>(&Wc[e * RECEPT]);
        float s = 0.f;
        #pragma unroll 4
        for (int r4 = 0; r4 < RECEPT / 4; ++r4) {
            float4 a = wd4[r4], bb = we4[r4];
            s += a.x * bb.x + a.y * bb.y + a.z * bb.z + a.w * bb.w;
        }
        if (d == e) s += EPS_V;
        G[d][e] = s;
    }
    __syncthreads();
    if (t == 0) {
        for (int i = 0; i < NUM_D; ++i) {
            float diag = G[i][i];
            for (int k = 0; k < i; ++k) diag -= Lm[i][k] * Lm[i][k];
            float di = sqrtf(diag);
            Lm[i][i] = di;
            float inv = 1.f / di;
            for (int jj = i + 1; jj < NUM_D; ++jj) {
                float s = G[jj][i];
                for (int k = 0; k < i; ++k) s -= Lm[jj][k] * Lm[i][k];
                Lm[jj][i] = s * inv;
            }
        }
    }
    __syncthreads();
    for (int r = t; r < RECEPT; r += 256) {
        float y[NUM_D];
        for (int d = 0; d < NUM_D; ++d) {
            float s = Wc[d * RECEPT + r];
            for (int k = 0; k < d; ++k) s -= Lm[d][k] * y[k];
            y[d] = s / Lm[d][d];
        }
        const int kk = r >> 5;          // 0..15
        const int g  = (r >> 3) & 3;    // k-group within 32
        const int j  = r & 7;
        for (int d = 0; d < NUM_D; ++d) {
            int cd = c * NUM_D + d;
            int ntile = cd >> 4;
            int nl = cd & 15;
            int lane = g * 16 + nl;
            int idx = (((ntile * 16 + kk) * 64) + lane) * 8 + j;
            wfrag[idx] = f2bf(y[d]);
        }
    }
}

// ---------------------------------------------------------------------------
// Main: 1024 blocks (b = bid>>1, half h = bid&1) x 256 thr (4 waves), one
// generation (4 blocks/CU, 16 waves/CU). ARCH-REGISTER BUDGET <= ~60 so the
// 64/64 arch/AGPR split at (256,4) holds without spill:
//  - staging: 4-deep load pairs with 1-batch lookahead (peak 8 f32x4 = 32)
//  - B: loaded per-kstep (2 short8 = 8 regs), latency hidden by 4-wave TLP
//  - acc (8 f32x4) lives in AGPRs
// ---------------------------------------------------------------------------
__global__ __launch_bounds__(256, 4) void main_kernel(
        const float* __restrict__ x,
        const unsigned short* __restrict__ wfrag,
        float* __restrict__ out) {
    __shared__ char lds[XBYTES];
    const int bid = blockIdx.x;
    const int b = bid >> 1;
    const int h = bid & 1;
    const int t = threadIdx.x;
    const int lane = t & 63;
    const int wv = t >> 6;          // 0..3
    const int rl = lane & 15;
    const int gl = lane >> 4;
    const int nt0 = wv * 2;         // this wave's first ntile

    const char* slice = (const char*)(x + (size_t)b * LROW + h * 16384);

#define XLOAD(dst_, i_) \
    dst_ = __builtin_nontemporal_load( \
        reinterpret_cast<const f32x4*>(slice + ((i_) * 256 + t) * 16))
#define XWRITE(src_, i_) \
    *reinterpret_cast<ushort4*>(lds + xsw(((i_) * 256 + t) * 8)) = cvt4(src_)

    // ---- staging: 4-deep batches, 1-batch lookahead (peak 32 regs) ----
    {
        f32x4 p0, p1, p2, p3, q0, q1, q2, q3;
        XLOAD(p0, 0);  XLOAD(p1, 1);  XLOAD(p2, 2);  XLOAD(p3, 3);
        XLOAD(q0, 4);  XLOAD(q1, 5);  XLOAD(q2, 6);  XLOAD(q3, 7);
        XWRITE(p0, 0); XWRITE(p1, 1); XWRITE(p2, 2); XWRITE(p3, 3);
        XLOAD(p0, 8);  XLOAD(p1, 9);  XLOAD(p2, 10); XLOAD(p3, 11);
        XWRITE(q0, 4); XWRITE(q1, 5); XWRITE(q2, 6); XWRITE(q3, 7);
        XLOAD(q0, 12); XLOAD(q1, 13); XLOAD(q2, 14); XLOAD(q3, 15);
        XWRITE(p0, 8); XWRITE(p1, 9); XWRITE(p2, 10); XWRITE(p3, 11);
        XWRITE(q0, 12); XWRITE(q1, 13); XWRITE(q2, 14); XWRITE(q3, 15);
        // 64 tail chunks (256-elem overlap; wraps to row start for h==1)
        const char* tsrc = h ? (const char*)(x + (size_t)b * LROW)
                             : slice + 65536;
        if (t < 64) {
            f32x4 vt = __builtin_nontemporal_load(
                reinterpret_cast<const f32x4*>(tsrc + t * 16));
            *reinterpret_cast<ushort4*>(lds + xsw((4096 + t) * 8)) = cvt4(vt);
        }
    }
#undef XLOAD
#undef XWRITE

    f32x4 a00 = {0,0,0,0}, a01 = {0,0,0,0};
    f32x4 a10 = {0,0,0,0}, a11 = {0,0,0,0};
    f32x4 a20 = {0,0,0,0}, a21 = {0,0,0,0};
    f32x4 a30 = {0,0,0,0}, a31 = {0,0,0,0};

    __syncthreads();        // x slice visible to all waves

#define BLOAD(dst_, kk_, ni_) \
    dst_ = *reinterpret_cast<const short8*>( \
        wfrag + ((size_t)(((nt0 + (ni_)) * 16 + (kk_)) * 64 + lane)) * 8)
#define AREAD(dst_, mi_, kk_) \
    dst_ = *reinterpret_cast<const short8*>( \
        lds + xsw(((mi_) * 16 + rl) * 512 + (kk_) * 64 + gl * 16))
#define MF(acc_, af_, bf_) \
    acc_ = __builtin_amdgcn_mfma_f32_16x16x32_bf16(af_, bf_, acc_, 0, 0, 0)

// one K-step: load 2 B frags (8 regs) + 4 A frags (16 regs), 8 MFMAs
#define KSTEP(kk_) { \
    short8 bA, bB, af0, af1, af2, af3; \
    BLOAD(bA, kk_, 0); BLOAD(bB, kk_, 1); \
    AREAD(af0, 0, kk_); AREAD(af1, 1, kk_); \
    AREAD(af2, 2, kk_); AREAD(af3, 3, kk_); \
    MF(a00, af0, bA); MF(a01, af0, bB); \
    MF(a10, af1, bA); MF(a11, af1, bB); \
    MF(a20, af2, bA); MF(a21, af2, bB); \
    MF(a30, af3, bA); MF(a31, af3, bB); }

    KSTEP(0)  KSTEP(1)  KSTEP(2)  KSTEP(3)
    KSTEP(4)  KSTEP(5)  KSTEP(6)  KSTEP(7)
    KSTEP(8)  KSTEP(9)  KSTEP(10) KSTEP(11)
    KSTEP(12) KSTEP(13) KSTEP(14) KSTEP(15)

#undef KSTEP
#undef MF
#undef AREAD
#undef BLOAD

    // epilogue: q = sum over 8 d-columns of P^2 (lane bits 0..2), sqrt,
    // sum over this block's 64 windows, atomics (mean weight 1/128).
#define SQSUM(s_, A_) { \
    _Pragma("unroll") \
    for (int r = 0; r < 4; ++r) { \
        float p = (A_)[r]; float qq = p * p; \
        qq += __shfl_xor(qq, 1); \
        qq += __shfl_xor(qq, 2); \
        qq += __shfl_xor(qq, 4); \
        s_ += sqrtf(qq); } }

    float s0 = 0.f, s1 = 0.f;
    SQSUM(s0, a00) SQSUM(s0, a10) SQSUM(s0, a20) SQSUM(s0, a30)
    SQSUM(s1, a01) SQSUM(s1, a11) SQSUM(s1, a21) SQSUM(s1, a31)
#undef SQSUM
    s0 += __shfl_xor(s0, 16); s0 += __shfl_xor(s0, 32);
    s1 += __shfl_xor(s1, 16); s1 += __shfl_xor(s1, 32);
    if (lane < 16 && (lane & 7) == 0) {
        int c0 = (wv * 32 + lane) >> 3;
        atomicAdd(&out[b * NUM_C + c0], s0 * (1.0f / 128.0f));
        atomicAdd(&out[b * NUM_C + c0 + 2], s1 * (1.0f / 128.0f));
    }
}

extern "C" void kernel_launch(void* const* d_in, const int* in_sizes, int n_in,
                              void* d_out, int out_size, void* d_ws, size_t ws_size,
                              hipStream_t stream) {
    (void)in_sizes; (void)n_in; (void)ws_size; (void)out_size;
    const float* x      = (const float*)d_in[0];
    const float* weight = (const float*)d_in[1];
    float* out = (float*)d_out;
    unsigned short* wfrag = (unsigned short*)d_ws;   // needs 128 KiB scratch

    prep_kernel<<<16, 256, 0, stream>>>(weight, wfrag, out);
    main_kernel<<<1024, 256, 0, stream>>>(x, wfrag, out);
}

// Round 15
// 34.095 us; speedup vs baseline: 29.9061x; 1.7369x over previous
//
#include <hip/hip_runtime.h>
#include <hip/hip_bf16.h>

#define NUM_C  16
#define NUM_D  8
#define RECEPT 512
#define LROW   32768
#define EPS_V  1e-4f

// per-block x slice: 64 windows * 256 stride + 256 overlap = 16640 bf16
// = 33280 B; +headroom for xsw (sets bits 4-6) -> 33536
#define XBYTES 33536

typedef __attribute__((ext_vector_type(8))) short short8;
typedef __attribute__((ext_vector_type(4))) float f32x4;

__device__ __forceinline__ unsigned short f2bf(float f) {
    unsigned int u = __builtin_bit_cast(unsigned int, f);
    u += 0x7fffu + ((u >> 16) & 1u);   // round-to-nearest-even
    return (unsigned short)(u >> 16);
}

// XOR swizzle on byte address in the bf16 x LDS slice (involution; applied on
// both staging writes and A-fragment reads; breaks the 512B window stride).
__device__ __forceinline__ int xsw(int a) { return a ^ (((a >> 9) & 7) << 4); }

__device__ __forceinline__ ushort4 cvt4(f32x4 v) {
    ushort4 h;
    h.x = f2bf(v[0]); h.y = f2bf(v[1]); h.z = f2bf(v[2]); h.w = f2bf(v[3]);
    return h;
}

// ---------------------------------------------------------------------------
// Prep (16 blocks x 256 thr): per c: G = W W^T + eps I ; chol; Wt = L^{-1} W ;
// store Wt bf16 in MFMA B-fragment order:
//   wfrag[ntile(8)][kk(16)][lane(64)][j(8)]
//   value = Wt[cd = ntile*16 + (lane&15)][r = kk*32 + (lane>>4)*8 + j]
// Also zeroes d_out.
// ---------------------------------------------------------------------------
__global__ void prep_kernel(const float* __restrict__ weight,
                            unsigned short* __restrict__ wfrag,
                            float* __restrict__ out) {
    __shared__ float Wc[NUM_D * RECEPT];
    __shared__ float G[NUM_D][NUM_D];
    __shared__ float Lm[NUM_D][NUM_D];
    const int c = blockIdx.x;
    const int t = threadIdx.x;  // 256 threads

    out[c * 256 + t] = 0.f;
    out[c * 256 + t + 4096] = 0.f;

    const float4* wsrc4 = reinterpret_cast<const float4*>(
        weight + (size_t)c * NUM_D * RECEPT);
    float4* Wc4 = reinterpret_cast<float4*>(Wc);
    #pragma unroll
    for (int i = 0; i < 4; ++i) Wc4[t + i * 256] = wsrc4[t + i * 256];
    __syncthreads();

    if (t < 64) {
        int d = t >> 3, e = t & 7;
        const float4* wd4 = reinterpret_cast<const float4*>(&Wc[d * RECEPT]);
        const float4* we4 = reinterpret_cast<const float4*>(&Wc[e * RECEPT]);
        float s = 0.f;
        #pragma unroll 4
        for (int r4 = 0; r4 < RECEPT / 4; ++r4) {
            float4 a = wd4[r4], bb = we4[r4];
            s += a.x * bb.x + a.y * bb.y + a.z * bb.z + a.w * bb.w;
        }
        if (d == e) s += EPS_V;
        G[d][e] = s;
    }
    __syncthreads();
    if (t == 0) {
        for (int i = 0; i < NUM_D; ++i) {
            float diag = G[i][i];
            for (int k = 0; k < i; ++k) diag -= Lm[i][k] * Lm[i][k];
            float di = sqrtf(diag);
            Lm[i][i] = di;
            float inv = 1.f / di;
            for (int jj = i + 1; jj < NUM_D; ++jj) {
                float s = G[jj][i];
                for (int k = 0; k < i; ++k) s -= Lm[jj][k] * Lm[i][k];
                Lm[jj][i] = s * inv;
            }
        }
    }
    __syncthreads();
    for (int r = t; r < RECEPT; r += 256) {
        float y[NUM_D];
        for (int d = 0; d < NUM_D; ++d) {
            float s = Wc[d * RECEPT + r];
            for (int k = 0; k < d; ++k) s -= Lm[d][k] * y[k];
            y[d] = s / Lm[d][d];
        }
        const int kk = r >> 5;          // 0..15
        const int g  = (r >> 3) & 3;    // k-group within 32
        const int j  = r & 7;
        for (int d = 0; d < NUM_D; ++d) {
            int cd = c * NUM_D + d;
            int ntile = cd >> 4;
            int nl = cd & 15;
            int lane = g * 16 + nl;
            int idx = (((ntile * 16 + kk) * 64) + lane) * 8 + j;
            wfrag[idx] = f2bf(y[d]);
        }
    }
}

// ---------------------------------------------------------------------------
// Main: 1024 blocks (b = bid>>1, half h = bid&1) x 256 thr (4 waves), one
// generation (4 blocks/CU, 16 waves/CU). K-loop is ROLLED (#pragma unroll 2)
// so the scheduler cannot hoist loads across the back-edge -> live set ~95
// regs < the (256,4) 128-reg cap -> no scratch spill (R13/R14's 95 MB
// WRITE_SIZE came from hoisting in the straight-line unrolled body).
// Plain (cached) loads — nt reverted with the L2-thrash theory.
// ---------------------------------------------------------------------------
__global__ __launch_bounds__(256, 4) void main_kernel(
        const float* __restrict__ x,
        const unsigned short* __restrict__ wfrag,
        float* __restrict__ out) {
    __shared__ char lds[XBYTES];
    const int bid = blockIdx.x;
    const int b = bid >> 1;
    const int h = bid & 1;
    const int t = threadIdx.x;
    const int lane = t & 63;
    const int wv = t >> 6;          // 0..3
    const int rl = lane & 15;
    const int gl = lane >> 4;
    const int nt0 = wv * 2;         // this wave's first ntile

    const char* slice = (const char*)(x + (size_t)b * LROW + h * 16384);

#define XLOAD(dst_, i_) \
    dst_ = *reinterpret_cast<const f32x4*>(slice + ((i_) * 256 + t) * 16)
#define XWRITE(src_, i_) \
    *reinterpret_cast<ushort4*>(lds + xsw(((i_) * 256 + t) * 8)) = cvt4(src_)

    // ---- staging: 4-deep batches, 1-batch lookahead (peak 32 regs) ----
    {
        f32x4 p0, p1, p2, p3, q0, q1, q2, q3;
        XLOAD(p0, 0);  XLOAD(p1, 1);  XLOAD(p2, 2);  XLOAD(p3, 3);
        XLOAD(q0, 4);  XLOAD(q1, 5);  XLOAD(q2, 6);  XLOAD(q3, 7);
        XWRITE(p0, 0); XWRITE(p1, 1); XWRITE(p2, 2); XWRITE(p3, 3);
        XLOAD(p0, 8);  XLOAD(p1, 9);  XLOAD(p2, 10); XLOAD(p3, 11);
        XWRITE(q0, 4); XWRITE(q1, 5); XWRITE(q2, 6); XWRITE(q3, 7);
        XLOAD(q0, 12); XLOAD(q1, 13); XLOAD(q2, 14); XLOAD(q3, 15);
        XWRITE(p0, 8); XWRITE(p1, 9); XWRITE(p2, 10); XWRITE(p3, 11);
        XWRITE(q0, 12); XWRITE(q1, 13); XWRITE(q2, 14); XWRITE(q3, 15);
        // 64 tail chunks (256-elem overlap; wraps to row start for h==1)
        const char* tsrc = h ? (const char*)(x + (size_t)b * LROW)
                             : slice + 65536;
        if (t < 64) {
            f32x4 vt = *reinterpret_cast<const f32x4*>(tsrc + t * 16);
            *reinterpret_cast<ushort4*>(lds + xsw((4096 + t) * 8)) = cvt4(vt);
        }
    }
#undef XLOAD
#undef XWRITE

    f32x4 a00 = {0,0,0,0}, a01 = {0,0,0,0};
    f32x4 a10 = {0,0,0,0}, a11 = {0,0,0,0};
    f32x4 a20 = {0,0,0,0}, a21 = {0,0,0,0};
    f32x4 a30 = {0,0,0,0}, a31 = {0,0,0,0};

    __syncthreads();        // x slice visible to all waves

    // per-wave B pointers; stride per kk = 64 lanes * 8 shorts = 512 elems
    const unsigned short* bptr0 = wfrag + ((size_t)(nt0 * 16) * 64 + lane) * 8;
    const unsigned short* bptr1 = wfrag + ((size_t)((nt0 + 1) * 16) * 64 + lane) * 8;
    const int abase = rl * 512;    // byte base of this lane's window row 0

    #pragma unroll 2
    for (int kk = 0; kk < 16; ++kk) {
        const int kb = kk * 64 + gl * 16;      // byte offset along k
        short8 bA = *reinterpret_cast<const short8*>(bptr0);
        short8 bB = *reinterpret_cast<const short8*>(bptr1);
        bptr0 += 512; bptr1 += 512;
        short8 af0 = *reinterpret_cast<const short8*>(lds + xsw(abase + kb));
        short8 af1 = *reinterpret_cast<const short8*>(lds + xsw(abase + 8192 + kb));
        short8 af2 = *reinterpret_cast<const short8*>(lds + xsw(abase + 16384 + kb));
        short8 af3 = *reinterpret_cast<const short8*>(lds + xsw(abase + 24576 + kb));
        a00 = __builtin_amdgcn_mfma_f32_16x16x32_bf16(af0, bA, a00, 0, 0, 0);
        a01 = __builtin_amdgcn_mfma_f32_16x16x32_bf16(af0, bB, a01, 0, 0, 0);
        a10 = __builtin_amdgcn_mfma_f32_16x16x32_bf16(af1, bA, a10, 0, 0, 0);
        a11 = __builtin_amdgcn_mfma_f32_16x16x32_bf16(af1, bB, a11, 0, 0, 0);
        a20 = __builtin_amdgcn_mfma_f32_16x16x32_bf16(af2, bA, a20, 0, 0, 0);
        a21 = __builtin_amdgcn_mfma_f32_16x16x32_bf16(af2, bB, a21, 0, 0, 0);
        a30 = __builtin_amdgcn_mfma_f32_16x16x32_bf16(af3, bA, a30, 0, 0, 0);
        a31 = __builtin_amdgcn_mfma_f32_16x16x32_bf16(af3, bB, a31, 0, 0, 0);
    }

    // epilogue: q = sum over 8 d-columns of P^2 (lane bits 0..2), sqrt,
    // sum over this block's 64 windows, atomics (mean weight 1/128).
#define SQSUM(s_, A_) { \
    _Pragma("unroll") \
    for (int r = 0; r < 4; ++r) { \
        float p = (A_)[r]; float qq = p * p; \
        qq += __shfl_xor(qq, 1); \
        qq += __shfl_xor(qq, 2); \
        qq += __shfl_xor(qq, 4); \
        s_ += sqrtf(qq); } }

    float s0 = 0.f, s1 = 0.f;
    SQSUM(s0, a00) SQSUM(s0, a10) SQSUM(s0, a20) SQSUM(s0, a30)
    SQSUM(s1, a01) SQSUM(s1, a11) SQSUM(s1, a21) SQSUM(s1, a31)
#undef SQSUM
    s0 += __shfl_xor(s0, 16); s0 += __shfl_xor(s0, 32);
    s1 += __shfl_xor(s1, 16); s1 += __shfl_xor(s1, 32);
    if (lane < 16 && (lane & 7) == 0) {
        int c0 = (wv * 32 + lane) >> 3;
        atomicAdd(&out[b * NUM_C + c0], s0 * (1.0f / 128.0f));
        atomicAdd(&out[b * NUM_C + c0 + 2], s1 * (1.0f / 128.0f));
    }
}

extern "C" void kernel_launch(void* const* d_in, const int* in_sizes, int n_in,
                              void* d_out, int out_size, void* d_ws, size_t ws_size,
                              hipStream_t stream) {
    (void)in_sizes; (void)n_in; (void)ws_size; (void)out_size;
    const float* x      = (const float*)d_in[0];
    const float* weight = (const float*)d_in[1];
    float* out = (float*)d_out;
    unsigned short* wfrag = (unsigned short*)d_ws;   // needs 128 KiB scratch

    prep_kernel<<<16, 256, 0, stream>>>(weight, wfrag, out);
    main_kernel<<<1024, 256, 0, stream>>>(x, wfrag, out);
}

// Round 16
// 32.483 us; speedup vs baseline: 31.3903x; 1.0496x over previous
//
#include <hip/hip_runtime.h>
#include <hip/hip_bf16.h>

#define NUM_C  16
#define NUM_D  8
#define RECEPT 512
#define LROW   32768
#define EPS_V  1e-4f

// per-block x slice: 64 windows * 256 stride + 256 overlap = 16640 bf16
// = 33280 B; +headroom for xsw (sets bits 4-6) -> 33536
#define XBYTES 33536

typedef __attribute__((ext_vector_type(8))) short short8;
typedef __attribute__((ext_vector_type(4))) float f32x4;

__device__ __forceinline__ unsigned short f2bf(float f) {
    unsigned int u = __builtin_bit_cast(unsigned int, f);
    u += 0x7fffu + ((u >> 16) & 1u);   // round-to-nearest-even
    return (unsigned short)(u >> 16);
}

// XOR swizzle on byte address in the bf16 x LDS slice (involution; applied on
// both staging writes and A-fragment reads; breaks the 512B window stride).
__device__ __forceinline__ int xsw(int a) { return a ^ (((a >> 9) & 7) << 4); }

__device__ __forceinline__ ushort4 cvt4(f32x4 v) {
    ushort4 h;
    h.x = f2bf(v[0]); h.y = f2bf(v[1]); h.z = f2bf(v[2]); h.w = f2bf(v[3]);
    return h;
}

// ---------------------------------------------------------------------------
// Prep (16 blocks x 256 thr): per c: G = W W^T + eps I ; chol; Wt = L^{-1} W ;
// store Wt bf16 in MFMA B-fragment order:
//   wfrag[ntile(8)][kk(16)][lane(64)][j(8)]
//   value = Wt[cd = ntile*16 + (lane&15)][r = kk*32 + (lane>>4)*8 + j]
// Also zeroes d_out.
// ---------------------------------------------------------------------------
__global__ void prep_kernel(const float* __restrict__ weight,
                            unsigned short* __restrict__ wfrag,
                            float* __restrict__ out) {
    __shared__ float Wc[NUM_D * RECEPT];
    __shared__ float G[NUM_D][NUM_D];
    __shared__ float Lm[NUM_D][NUM_D];
    const int c = blockIdx.x;
    const int t = threadIdx.x;  // 256 threads

    out[c * 256 + t] = 0.f;
    out[c * 256 + t + 4096] = 0.f;

    const float4* wsrc4 = reinterpret_cast<const float4*>(
        weight + (size_t)c * NUM_D * RECEPT);
    float4* Wc4 = reinterpret_cast<float4*>(Wc);
    #pragma unroll
    for (int i = 0; i < 4; ++i) Wc4[t + i * 256] = wsrc4[t + i * 256];
    __syncthreads();

    if (t < 64) {
        int d = t >> 3, e = t & 7;
        const float4* wd4 = reinterpret_cast<const float4*>(&Wc[d * RECEPT]);
        const float4* we4 = reinterpret_cast<const float4*>(&Wc[e * RECEPT]);
        float s = 0.f;
        #pragma unroll 4
        for (int r4 = 0; r4 < RECEPT / 4; ++r4) {
            float4 a = wd4[r4], bb = we4[r4];
            s += a.x * bb.x + a.y * bb.y + a.z * bb.z + a.w * bb.w;
        }
        if (d == e) s += EPS_V;
        G[d][e] = s;
    }
    __syncthreads();
    if (t == 0) {
        for (int i = 0; i < NUM_D; ++i) {
            float diag = G[i][i];
            for (int k = 0; k < i; ++k) diag -= Lm[i][k] * Lm[i][k];
            float di = sqrtf(diag);
            Lm[i][i] = di;
            float inv = 1.f / di;
            for (int jj = i + 1; jj < NUM_D; ++jj) {
                float s = G[jj][i];
                for (int k = 0; k < i; ++k) s -= Lm[jj][k] * Lm[i][k];
                Lm[jj][i] = s * inv;
            }
        }
    }
    __syncthreads();
    for (int r = t; r < RECEPT; r += 256) {
        float y[NUM_D];
        for (int d = 0; d < NUM_D; ++d) {
            float s = Wc[d * RECEPT + r];
            for (int k = 0; k < d; ++k) s -= Lm[d][k] * y[k];
            y[d] = s / Lm[d][d];
        }
        const int kk = r >> 5;          // 0..15
        const int g  = (r >> 3) & 3;    // k-group within 32
        const int j  = r & 7;
        for (int d = 0; d < NUM_D; ++d) {
            int cd = c * NUM_D + d;
            int ntile = cd >> 4;
            int nl = cd & 15;
            int lane = g * 16 + nl;
            int idx = (((ntile * 16 + kk) * 64) + lane) * 8 + j;
            wfrag[idx] = f2bf(y[d]);
        }
    }
}

// ---------------------------------------------------------------------------
// Main: 1024 blocks (b = bid>>1, half h = bid&1) x 256 thr (4 waves), one
// generation (4 blocks/CU, 16 waves/CU). K-loop ROLLED (#pragma unroll 2) so
// loads can't be hoisted across the back-edge -> no spill (R15-verified).
// x staged via NON-TEMPORAL loads: x is zero-reuse streaming, nt keeps the
// 128 KB wfrag L2-resident (R13-verified: FETCH 186->82 MB) and avoids L3
// dirty-eviction writebacks of harness poison data.
// ---------------------------------------------------------------------------
__global__ __launch_bounds__(256, 4) void main_kernel(
        const float* __restrict__ x,
        const unsigned short* __restrict__ wfrag,
        float* __restrict__ out) {
    __shared__ char lds[XBYTES];
    const int bid = blockIdx.x;
    const int b = bid >> 1;
    const int h = bid & 1;
    const int t = threadIdx.x;
    const int lane = t & 63;
    const int wv = t >> 6;          // 0..3
    const int rl = lane & 15;
    const int gl = lane >> 4;
    const int nt0 = wv * 2;         // this wave's first ntile

    const char* slice = (const char*)(x + (size_t)b * LROW + h * 16384);

#define XLOAD(dst_, i_) \
    dst_ = __builtin_nontemporal_load( \
        reinterpret_cast<const f32x4*>(slice + ((i_) * 256 + t) * 16))
#define XWRITE(src_, i_) \
    *reinterpret_cast<ushort4*>(lds + xsw(((i_) * 256 + t) * 8)) = cvt4(src_)

    // ---- staging: 4-deep batches, 1-batch lookahead (peak 32 regs) ----
    {
        f32x4 p0, p1, p2, p3, q0, q1, q2, q3;
        XLOAD(p0, 0);  XLOAD(p1, 1);  XLOAD(p2, 2);  XLOAD(p3, 3);
        XLOAD(q0, 4);  XLOAD(q1, 5);  XLOAD(q2, 6);  XLOAD(q3, 7);
        XWRITE(p0, 0); XWRITE(p1, 1); XWRITE(p2, 2); XWRITE(p3, 3);
        XLOAD(p0, 8);  XLOAD(p1, 9);  XLOAD(p2, 10); XLOAD(p3, 11);
        XWRITE(q0, 4); XWRITE(q1, 5); XWRITE(q2, 6); XWRITE(q3, 7);
        XLOAD(q0, 12); XLOAD(q1, 13); XLOAD(q2, 14); XLOAD(q3, 15);
        XWRITE(p0, 8); XWRITE(p1, 9); XWRITE(p2, 10); XWRITE(p3, 11);
        XWRITE(q0, 12); XWRITE(q1, 13); XWRITE(q2, 14); XWRITE(q3, 15);
        // 64 tail chunks (256-elem overlap; wraps to row start for h==1)
        const char* tsrc = h ? (const char*)(x + (size_t)b * LROW)
                             : slice + 65536;
        if (t < 64) {
            f32x4 vt = __builtin_nontemporal_load(
                reinterpret_cast<const f32x4*>(tsrc + t * 16));
            *reinterpret_cast<ushort4*>(lds + xsw((4096 + t) * 8)) = cvt4(vt);
        }
    }
#undef XLOAD
#undef XWRITE

    f32x4 a00 = {0,0,0,0}, a01 = {0,0,0,0};
    f32x4 a10 = {0,0,0,0}, a11 = {0,0,0,0};
    f32x4 a20 = {0,0,0,0}, a21 = {0,0,0,0};
    f32x4 a30 = {0,0,0,0}, a31 = {0,0,0,0};

    __syncthreads();        // x slice visible to all waves

    // per-wave B pointers; stride per kk = 64 lanes * 8 shorts = 512 elems
    const unsigned short* bptr0 = wfrag + ((size_t)(nt0 * 16) * 64 + lane) * 8;
    const unsigned short* bptr1 = wfrag + ((size_t)((nt0 + 1) * 16) * 64 + lane) * 8;
    const int abase = rl * 512;    // byte base of this lane's window row 0

    #pragma unroll 2
    for (int kk = 0; kk < 16; ++kk) {
        const int kb = kk * 64 + gl * 16;      // byte offset along k
        short8 bA = *reinterpret_cast<const short8*>(bptr0);
        short8 bB = *reinterpret_cast<const short8*>(bptr1);
        bptr0 += 512; bptr1 += 512;
        short8 af0 = *reinterpret_cast<const short8*>(lds + xsw(abase + kb));
        short8 af1 = *reinterpret_cast<const short8*>(lds + xsw(abase + 8192 + kb));
        short8 af2 = *reinterpret_cast<const short8*>(lds + xsw(abase + 16384 + kb));
        short8 af3 = *reinterpret_cast<const short8*>(lds + xsw(abase + 24576 + kb));
        a00 = __builtin_amdgcn_mfma_f32_16x16x32_bf16(af0, bA, a00, 0, 0, 0);
        a01 = __builtin_amdgcn_mfma_f32_16x16x32_bf16(af0, bB, a01, 0, 0, 0);
        a10 = __builtin_amdgcn_mfma_f32_16x16x32_bf16(af1, bA, a10, 0, 0, 0);
        a11 = __builtin_amdgcn_mfma_f32_16x16x32_bf16(af1, bB, a11, 0, 0, 0);
        a20 = __builtin_amdgcn_mfma_f32_16x16x32_bf16(af2, bA, a20, 0, 0, 0);
        a21 = __builtin_amdgcn_mfma_f32_16x16x32_bf16(af2, bB, a21, 0, 0, 0);
        a30 = __builtin_amdgcn_mfma_f32_16x16x32_bf16(af3, bA, a30, 0, 0, 0);
        a31 = __builtin_amdgcn_mfma_f32_16x16x32_bf16(af3, bB, a31, 0, 0, 0);
    }

    // epilogue: q = sum over 8 d-columns of P^2 (lane bits 0..2), sqrt,
    // sum over this block's 64 windows, atomics (mean weight 1/128).
#define SQSUM(s_, A_) { \
    _Pragma("unroll") \
    for (int r = 0; r < 4; ++r) { \
        float p = (A_)[r]; float qq = p * p; \
        qq += __shfl_xor(qq, 1); \
        qq += __shfl_xor(qq, 2); \
        qq += __shfl_xor(qq, 4); \
        s_ += sqrtf(qq); } }

    float s0 = 0.f, s1 = 0.f;
    SQSUM(s0, a00) SQSUM(s0, a10) SQSUM(s0, a20) SQSUM(s0, a30)
    SQSUM(s1, a01) SQSUM(s1, a11) SQSUM(s1, a21) SQSUM(s1, a31)
#undef SQSUM
    s0 += __shfl_xor(s0, 16); s0 += __shfl_xor(s0, 32);
    s1 += __shfl_xor(s1, 16); s1 += __shfl_xor(s1, 32);
    if (lane < 16 && (lane & 7) == 0) {
        int c0 = (wv * 32 + lane) >> 3;
        atomicAdd(&out[b * NUM_C + c0], s0 * (1.0f / 128.0f));
        atomicAdd(&out[b * NUM_C + c0 + 2], s1 * (1.0f / 128.0f));
    }
}

extern "C" void kernel_launch(void* const* d_in, const int* in_sizes, int n_in,
                              void* d_out, int out_size, void* d_ws, size_t ws_size,
                              hipStream_t stream) {
    (void)in_sizes; (void)n_in; (void)ws_size; (void)out_size;
    const float* x      = (const float*)d_in[0];
    const float* weight = (const float*)d_in[1];
    float* out = (float*)d_out;
    unsigned short* wfrag = (unsigned short*)d_ws;   // needs 128 KiB scratch

    prep_kernel<<<16, 256, 0, stream>>>(weight, wfrag, out);
    main_kernel<<<1024, 256, 0, stream>>>(x, wfrag, out);
}